// Round 9
// baseline (80.835 us; speedup 1.0000x reference)
//
#include <hip/hip_runtime.h>
#include <hip/hip_bf16.h>

#define HWPX 589824          // 768*768
#define MPIX 2359296         // 4*768*768
#define EPSF 1e-7f
#define LN2F 0.6931471805599453f
#define TILES 9              // 9 tiles * 256 px = 2304 px per block
#define PXB  2304            // 256 blocks/image -> never straddles a batch
#define NBLK 1024            // MPIX / PXB = exactly 4 blocks/CU

// ws float layout:
// [0..2]   cls: bce_log2sum, inter, sum_p
// [3..5]   pred ch0 vs (1-tfg): bce_log2sum, inter, sum_p
// [6..21]  a_sum[k]  = sum log2(1-pc), channels k=0..15 (pred ch 1..16)
// [22..37] sum_p[k]
// [38..293]  segD[n*16+k]   (log2 units)
// [294..549] segP[n*16+k]
// [550..565] cntf[n]  float counts of ids 1..16

typedef __attribute__((ext_vector_type(8))) short bf16x8;
typedef __attribute__((ext_vector_type(4))) float f32x4;

__device__ __forceinline__ short bfc(float x) {   // compiler emits v_cvt_pk_bf16_f32
    union { __hip_bfloat16 h; short s; } u;
    u.h = __float2bfloat16(x);
    return u.s;
}

__device__ __forceinline__ float wave_sum64(float v) {
#pragma unroll
    for (int o = 32; o; o >>= 1) v += __shfl_xor(v, o, 64);
    return v;
}

#define GLD16(gsrc, ldst) __builtin_amdgcn_global_load_lds( \
    (const __attribute__((address_space(1))) void*)(gsrc),  \
    (__attribute__((address_space(3))) void*)(ldst), 16, 0, 0)

#define WAITV(n) asm volatile("s_waitcnt vmcnt(" #n ")" ::: "memory")

__global__ __launch_bounds__(512, 8) void loss_main(
    const float* __restrict__ pred, const float* __restrict__ cls,
    const int* __restrict__ tm, float* __restrict__ acc)
{
    __shared__ float stage[2][16][256];  // 32 KB: [buf][ch row][px], XOR-swizzled slots
    __shared__ int   tmt[2][256];        // 2 KB: tm tile
    __shared__ float gD[256], gP[256];   // block segD/segP
    __shared__ float sCh[3][16][8];      // {sum_log2_1mp, sum_p, cnt}[ch][wave]
    __shared__ float sC6[6][8];          // cls/ch0 partials

    const int tid  = threadIdx.x;
    const int w    = tid >> 6;       // wave 0..7
    const int lane = tid & 63;
    const int g    = lane >> 4;      // px subgroup 0..3
    const int q    = lane & 15;      // B: channel idx / A: bin idx

    const long base = (long)blockIdx.x * PXB;
    const int b   = (int)(base / HWPX);
    const int off = (int)(base % HWPX);

    const int* trow = tm + (long)b * HWPX + off;
    const float* pbase17 = pred + (long)b * 17 * (long)HWPX + off;

    if (tid < 256) { gD[tid] = 0.f; gP[tid] = 0.f; }

    // stage tile t_ into buffer buf_: wave w stages channel rows w, w+8 (1KB coalesced
    // each, source XOR-pre-swizzled per row so reads can be bank-conflict-free);
    // wave 0 additionally stages the 1KB tm row.
#define STAGE(t_, buf_) do {                                                      \
        const int _r0 = w, _r1 = w + 8;                                           \
        GLD16(pbase17 + (long)(1 + _r0) * HWPX + (t_) * 256 + ((lane ^ (_r0 & 7)) << 2), \
              &stage[buf_][_r0][0]);                                              \
        GLD16(pbase17 + (long)(1 + _r1) * HWPX + (t_) * 256 + ((lane ^ (_r1 & 7)) << 2), \
              &stage[buf_][_r1][0]);                                              \
        if (w == 0) GLD16(trow + (t_) * 256 + (lane << 2), &tmt[buf_][0]);        \
    } while (0)

    STAGE(0, 0);

    f32x4 aD = {0.f, 0.f, 0.f, 0.f};
    f32x4 aP = {0.f, 0.f, 0.f, 0.f};
    float sl2 = 0.f, sp = 0.f, cf = 0.f;
    const int tgt = q + 1;
    const int s4 = w * 8 + g * 2;    // even float4/int4 slot of this lane's 8 px
    const int k8 = q & 7;            // swizzle key (matches store-side row key)

#pragma unroll 1
    for (int t = 0; t < TILES; ++t) {
        const int bi = t & 1;
        if (t + 1 < TILES) {
            STAGE(t + 1, bi ^ 1);
            if (w == 0) WAITV(3); else WAITV(2);   // tile t's staging complete (counted, not 0)
        } else {
            WAITV(0);
        }
        __syncthreads();                            // all waves' tile-t rows visible

        const float4 pa = ((const float4*)&stage[bi][q][0])[s4 ^ k8];
        const float4 pb = ((const float4*)&stage[bi][q][0])[(s4 + 1) ^ k8];
        const int4   ta = ((const int4*)&tmt[bi][0])[s4];        // broadcast within g-group
        const int4   tb = ((const int4*)&tmt[bi][0])[s4 + 1];

        const float pv[8] = {pa.x,pa.y,pa.z,pa.w,pb.x,pb.y,pb.z,pb.w};
        const int   tv[8] = {ta.x,ta.y,ta.z,ta.w,tb.x,tb.y,tb.z,tb.w};
        bf16x8 av, bD, bP;
#pragma unroll
        for (int j = 0; j < 8; ++j) {
            const float p  = pv[j];
            const float pc = fminf(fmaxf(p, EPSF), 1.0f - EPSF);
            const float l2p  = __log2f(pc);          // raw v_log_f32
            const float l21p = __log2f(1.0f - pc);
            sl2 += l21p;
            sp  += p;
            bD[j] = bfc(l21p - l2p);                 // log2-units; ln2 applied in finalize
            bP[j] = bfc(p);
            const bool m = (tv[j] == tgt);
            av[j] = m ? (short)0x3F80 : (short)0;
            cf += m ? 1.f : 0.f;
        }
        aD = __builtin_amdgcn_mfma_f32_16x16x32_bf16(av, bD, aD, 0, 0, 0);
        aP = __builtin_amdgcn_mfma_f32_16x16x32_bf16(av, bP, aP, 0, 0, 0);
        __syncthreads();                            // everyone done reading buf bi
    }
#undef STAGE

    // per-channel scalars: reduce across the 4 px-subgroups (lanes l, l^16, l^32, l^48)
    sl2 += __shfl_xor(sl2, 16, 64); sl2 += __shfl_xor(sl2, 32, 64);
    sp  += __shfl_xor(sp,  16, 64); sp  += __shfl_xor(sp,  32, 64);
    cf  += __shfl_xor(cf,  16, 64); cf  += __shfl_xor(cf,  32, 64);
    if (lane < 16) { sCh[0][q][w] = sl2; sCh[1][q][w] = sp; sCh[2][q][w] = cf; }

    // C-frag scatter: (n,k) with n = (lane>>4)*4 + r, k = q  (m89-verified layout)
#pragma unroll
    for (int r = 0; r < 4; ++r) {
        const int n = ((lane >> 4) << 2) + r;
        atomicAdd(&gD[n * 16 + q], aD[r]);   // one-shot LDS atomics (not the hot path)
        atomicAdd(&gP[n * 16 + q], aP[r]);
    }

    // ---- cls (vs tfg) and pred ch0 (vs 1-tfg): 2304 px = 512*4 + 64*4, coalesced ----
    const float* crow = cls + (long)b * HWPX + off;
    const float* zrow = pbase17;                      // pred channel 0
    float s0c=0.f,s1c=0.f,s2c=0.f, s00=0.f,s10=0.f,s20=0.f;
    const int nch = (tid < 64) ? 2 : 1;
    for (int chunk = 0; chunk < nch; ++chunk) {
        const int pb2 = (chunk == 0) ? tid * 4 : 2048 + tid * 4;
        const float4 ca = *(const float4*)(crow + pb2);
        const float4 za = *(const float4*)(zrow + pb2);
        const int4   ua = *(const int4*)(trow + pb2);
        const float cv[4] = {ca.x,ca.y,ca.z,ca.w};
        const float zv[4] = {za.x,za.y,za.z,za.w};
        const int   uv[4] = {ua.x,ua.y,ua.z,ua.w};
#pragma unroll
        for (int j = 0; j < 4; ++j) {
            const int t = uv[j];
            { const float p = cv[j];
              const float pc = fminf(fmaxf(p, EPSF), 1.0f - EPSF);
              const float lp = __log2f(pc), l1p = __log2f(1.0f - pc);
              const bool fg = (t > 0);
              s0c += fg ? lp : l1p; s1c += fg ? p : 0.f; s2c += p; }
            { const float p = zv[j];
              const float pc = fminf(fmaxf(p, EPSF), 1.0f - EPSF);
              const float lp = __log2f(pc), l1p = __log2f(1.0f - pc);
              const bool bg = (t == 0);
              s00 += bg ? lp : l1p; s10 += bg ? p : 0.f; s20 += p; }
        }
    }
    s0c = wave_sum64(s0c); s1c = wave_sum64(s1c); s2c = wave_sum64(s2c);
    s00 = wave_sum64(s00); s10 = wave_sum64(s10); s20 = wave_sum64(s20);
    if (lane == 0) {
        sC6[0][w]=s0c; sC6[1][w]=s1c; sC6[2][w]=s2c;
        sC6[3][w]=s00; sC6[4][w]=s10; sC6[5][w]=s20;
    }
    __syncthreads();

    if (tid < 256) {
        atomicAdd(&acc[38 + tid], gD[tid]);
        atomicAdd(&acc[294 + tid], gP[tid]);
    } else if (tid < 304) {
        const int i = tid - 256, qq = i >> 4, ii = i & 15;
        float t = 0.f;
#pragma unroll
        for (int ww = 0; ww < 8; ++ww) t += sCh[qq][ii][ww];
        atomicAdd(&acc[(qq == 0) ? (6 + ii) : (qq == 1) ? (22 + ii) : (550 + ii)], t);
    } else if (tid < 310) {
        const int i = tid - 304;
        float t = 0.f;
#pragma unroll
        for (int ww = 0; ww < 8; ++ww) t += sC6[i][ww];
        atomicAdd(&acc[i], t);
    }
}

__global__ void loss_final(const float* __restrict__ acc, float* __restrict__ out)
{
    __shared__ float L[16][16];
    __shared__ float s_fg;
    const int tid = threadIdx.x;
    const float Mf = (float)MPIX;

    if (tid == 0) {
        float s = 0.f;
        for (int n = 0; n < 16; ++n) s += acc[550 + n];
        s_fg = s;                      // # pixels with id>0 == sum(tfg)
    }
    __syncthreads();

    if (tid < 256) {
        const int n = tid >> 4, k = tid & 15;
        const float segD = acc[38 + n * 16 + k];    // log2 units
        const float segP = acc[294 + n * 16 + k];
        const float sump = acc[22 + k];
        const float cn   = acc[550 + n];
        const float bce  = (segD - acc[6 + k]) * LN2F / Mf;
        const float dice = 1.f - (2.f * segP + EPSF) / (sump + cn + EPSF);
        L[n][k] = bce + dice;
    }
    __syncthreads();

    if (tid < 64) {   // wave 0: greedy assignment on lanes 0..15
        const bool mine = (tid < 16);
        float total = 0.f;
        unsigned avail = mine ? 1u : 0u;
        for (int step = 0; step < 16; ++step) {
            float v = (mine && avail) ? L[step][tid] : 1e30f;
            int idx = tid;
            #pragma unroll
            for (int o = 8; o; o >>= 1) {
                const float ov = __shfl_xor(v, o, 64);
                const int   oi = __shfl_xor(idx, o, 64);
                if (ov < v || (ov == v && oi < idx)) { v = ov; idx = oi; }
            }
            if (tid == 0) total += v;
            if (tid == idx) avail = 0;
        }
        if (tid == 0) {
            const float cnt0 = Mf - s_fg;
            const float bce_c  = -acc[0] * LN2F / Mf;
            const float dice_c = 1.f - (2.f * acc[1] + EPSF) / (acc[2] + s_fg + EPSF);
            const float bce_0  = -acc[3] * LN2F / Mf;
            const float dice_0 = 1.f - (2.f * acc[4] + EPSF) / (acc[5] + cnt0 + EPSF);
            const float res = bce_c + dice_c + bce_0 + dice_0;
            out[0] = (res + total) / 16.f;
        }
    }
}

extern "C" void kernel_launch(void* const* d_in, const int* in_sizes, int n_in,
                              void* d_out, int out_size, void* d_ws, size_t ws_size,
                              hipStream_t stream)
{
    const float* pred = (const float*)d_in[0];
    const float* cls  = (const float*)d_in[1];
    const int*   tmi  = (const int*)d_in[2];
    float* acc = (float*)d_ws;

    hipMemsetAsync(d_ws, 0, 566 * sizeof(float), stream);

    loss_main<<<dim3(NBLK), 512, 0, stream>>>(pred, cls, tmi, acc);
    loss_final<<<1, 256, 0, stream>>>(acc, (float*)d_out);
}

// Round 10
// 69.409 us; speedup vs baseline: 1.1646x; 1.1646x over previous
//
#include <hip/hip_runtime.h>
#include <hip/hip_bf16.h>

#define HWPX 589824          // 768*768
#define MPIX 2359296         // 4*768*768
#define EPSF 1e-7f
#define LN2F 0.6931471805599453f
#define PXB  2304            // px per block; 256 blocks/image -> never straddles
#define NBLK 1024            // MPIX / PXB
#define MSTEPS 9             // 9 steps * (8 waves * 32 px) = 2304 px

// ws float layout:
// [0..2]   cls: bce_log2sum, inter, sum_p
// [3..5]   pred ch0 vs (1-tfg): bce_log2sum, inter, sum_p
// [6..21]  a_sum[k]  = sum log2(1-pc), channels k=0..15 (pred ch 1..16)
// [22..37] sum_p[k]
// [38..293]  segD[n*16+k]   (log2 units)
// [294..549] segP[n*16+k]
// [550..565] cntf[n]  float counts of ids 1..16

typedef __attribute__((ext_vector_type(8))) short bf16x8;
typedef __attribute__((ext_vector_type(4))) float f32x4;

__device__ __forceinline__ short bfc(float x) {   // compiler emits v_cvt_pk_bf16_f32
    union { __hip_bfloat16 h; short s; } u;
    u.h = __float2bfloat16(x);
    return u.s;
}

__device__ __forceinline__ float wave_sum64(float v) {
#pragma unroll
    for (int o = 32; o; o >>= 1) v += __shfl_xor(v, o, 64);
    return v;
}

struct Buf { float4 pa, pb; int4 ta, tb; };

__global__ __launch_bounds__(512, 6) void loss_main(
    const float* __restrict__ pred, const float* __restrict__ cls,
    const int* __restrict__ tm, float* __restrict__ acc)
{
    __shared__ float sD[8][256];     // per-wave segD C-frags
    __shared__ float sP[8][256];
    __shared__ float sCh[3][16][8];  // {sum_log2_1mp, sum_p, cnt}[ch/bin][wave]
    __shared__ float sC6[6][8];      // cls/ch0 partials

    const int tid  = threadIdx.x;
    const int w    = tid >> 6;       // wave 0..7
    const int lane = tid & 63;
    const int g    = lane >> 4;      // px subgroup 0..3
    const int q    = lane & 15;      // B: channel idx / A: bin idx

    const long base = (long)blockIdx.x * PXB;
    const int b   = (int)(base / HWPX);
    const int off = (int)(base % HWPX);

    const int*   trow = tm   + (long)b * HWPX + off;
    const float* prow = pred + ((long)b * 17 + 1 + q) * (long)HWPX + off;

    f32x4 aD = {0.f, 0.f, 0.f, 0.f};
    f32x4 aP = {0.f, 0.f, 0.f, 0.f};
    float sl2 = 0.f, sp = 0.f, cf = 0.f;
    const int tgt = q + 1;
    const int lbase = w * 32 + g * 8;

    // 3-deep register pipeline: LOAD(s+2) issues BEFORE MATH(s) each step;
    // buffer index is a compile-time constant under full unroll (no scratch),
    // sched_barrier(0) pins the order so loads stay ~2 steps ahead of use.
    Buf bf[3];
#define LOADS(S, B) do { const int _px = lbase + (S) * 256;              \
        bf[B].pa = *(const float4*)(prow + _px);                         \
        bf[B].pb = *(const float4*)(prow + _px + 4);                     \
        bf[B].ta = *(const int4*)(trow + _px);                           \
        bf[B].tb = *(const int4*)(trow + _px + 4); } while (0)

    LOADS(0, 0);
    LOADS(1, 1);

#pragma unroll
    for (int s = 0; s < MSTEPS; ++s) {
        if (s + 2 < MSTEPS) LOADS(s + 2, (s + 2) % 3);   // writes a dead buffer
        const Buf& cb = bf[s % 3];
        const float pv[8] = {cb.pa.x,cb.pa.y,cb.pa.z,cb.pa.w,cb.pb.x,cb.pb.y,cb.pb.z,cb.pb.w};
        const int   tv[8] = {cb.ta.x,cb.ta.y,cb.ta.z,cb.ta.w,cb.tb.x,cb.tb.y,cb.tb.z,cb.tb.w};
        bf16x8 av, bD, bP;
#pragma unroll
        for (int j = 0; j < 8; ++j) {
            const float p  = pv[j];
            const float pc = fminf(fmaxf(p, EPSF), 1.0f - EPSF);
            const float l2p  = __log2f(pc);          // raw v_log_f32
            const float l21p = __log2f(1.0f - pc);
            sl2 += l21p;
            sp  += p;
            bD[j] = bfc(l21p - l2p);                 // log2-units; ln2 applied in finalize
            bP[j] = bfc(p);
            const bool m = (tv[j] == tgt);
            av[j] = m ? (short)0x3F80 : (short)0;
            cf += m ? 1.f : 0.f;
        }
        aD = __builtin_amdgcn_mfma_f32_16x16x32_bf16(av, bD, aD, 0, 0, 0);
        aP = __builtin_amdgcn_mfma_f32_16x16x32_bf16(av, bP, aP, 0, 0, 0);
        __builtin_amdgcn_sched_barrier(0);           // keep pipeline order across steps
    }
#undef LOADS

    // reduce per-channel scalars across the 4 px-subgroups (lanes l, l^16, l^32, l^48)
    sl2 += __shfl_xor(sl2, 16, 64); sl2 += __shfl_xor(sl2, 32, 64);
    sp  += __shfl_xor(sp,  16, 64); sp  += __shfl_xor(sp,  32, 64);
    cf  += __shfl_xor(cf,  16, 64); cf  += __shfl_xor(cf,  32, 64);
    if (lane < 16) { sCh[0][q][w] = sl2; sCh[1][q][w] = sp; sCh[2][q][w] = cf; }

    *(f32x4*)&sD[w][lane * 4] = aD;   // element (n,k) at flat ((((n>>2)<<4)|k)<<2)|(n&3)
    *(f32x4*)&sP[w][lane * 4] = aP;

    // ---- cls (vs tfg) and pred ch0 (vs 1-tfg): 2304 px = 512*4 + 64*4 ----
    const float* crow = cls  + (long)b * HWPX + off;
    const float* zrow = pred + (long)b * 17 * (long)HWPX + off;   // channel 0
    float s0c=0.f,s1c=0.f,s2c=0.f, s00=0.f,s10=0.f,s20=0.f;
    const int nch = (tid < 64) ? 2 : 1;
    for (int chunk = 0; chunk < nch; ++chunk) {
        const int pbase = (chunk == 0) ? tid * 4 : 2048 + tid * 4;
        const float4 ca = *(const float4*)(crow + pbase);
        const float4 za = *(const float4*)(zrow + pbase);
        const int4   ua = *(const int4*)(trow + pbase);
        const float cv[4] = {ca.x,ca.y,ca.z,ca.w};
        const float zv[4] = {za.x,za.y,za.z,za.w};
        const int   uv[4] = {ua.x,ua.y,ua.z,ua.w};
#pragma unroll
        for (int j = 0; j < 4; ++j) {
            const int t = uv[j];
            { const float p = cv[j];
              const float pc = fminf(fmaxf(p, EPSF), 1.0f - EPSF);
              const float lp = __log2f(pc), l1p = __log2f(1.0f - pc);
              const bool fg = (t > 0);
              s0c += fg ? lp : l1p; s1c += fg ? p : 0.f; s2c += p; }
            { const float p = zv[j];
              const float pc = fminf(fmaxf(p, EPSF), 1.0f - EPSF);
              const float lp = __log2f(pc), l1p = __log2f(1.0f - pc);
              const bool bg = (t == 0);
              s00 += bg ? lp : l1p; s10 += bg ? p : 0.f; s20 += p; }
        }
    }
    s0c = wave_sum64(s0c); s1c = wave_sum64(s1c); s2c = wave_sum64(s2c);
    s00 = wave_sum64(s00); s10 = wave_sum64(s10); s20 = wave_sum64(s20);
    if (lane == 0) {
        sC6[0][w]=s0c; sC6[1][w]=s1c; sC6[2][w]=s2c;
        sC6[3][w]=s00; sC6[4][w]=s10; sC6[5][w]=s20;
    }
    __syncthreads();

    if (tid < 256) {
        const int n = tid >> 4, k = tid & 15;
        const int idx = ((((n >> 2) << 4) | k) << 2) | (n & 3);
        float dsum = 0.f, psum = 0.f;
#pragma unroll
        for (int ww = 0; ww < 8; ++ww) { dsum += sD[ww][idx]; psum += sP[ww][idx]; }
        atomicAdd(&acc[38 + n * 16 + k], dsum);
        atomicAdd(&acc[294 + n * 16 + k], psum);
    } else if (tid < 304) {
        const int i = tid - 256, qq = i >> 4, ii = i & 15;
        float t = 0.f;
#pragma unroll
        for (int ww = 0; ww < 8; ++ww) t += sCh[qq][ii][ww];
        atomicAdd(&acc[(qq == 0) ? (6 + ii) : (qq == 1) ? (22 + ii) : (550 + ii)], t);
    } else if (tid < 310) {
        const int i = tid - 304;
        float t = 0.f;
#pragma unroll
        for (int ww = 0; ww < 8; ++ww) t += sC6[i][ww];
        atomicAdd(&acc[i], t);
    }
}

__global__ void loss_final(const float* __restrict__ acc, float* __restrict__ out)
{
    __shared__ float L[16][16];
    __shared__ float s_fg;
    const int tid = threadIdx.x;
    const float Mf = (float)MPIX;

    if (tid == 0) {
        float s = 0.f;
        for (int n = 0; n < 16; ++n) s += acc[550 + n];
        s_fg = s;                      // # pixels with id>0 == sum(tfg)
    }
    __syncthreads();

    if (tid < 256) {
        const int n = tid >> 4, k = tid & 15;
        const float segD = acc[38 + n * 16 + k];    // log2 units
        const float segP = acc[294 + n * 16 + k];
        const float sump = acc[22 + k];
        const float cn   = acc[550 + n];
        const float bce  = (segD - acc[6 + k]) * LN2F / Mf;
        const float dice = 1.f - (2.f * segP + EPSF) / (sump + cn + EPSF);
        L[n][k] = bce + dice;
    }
    __syncthreads();

    if (tid < 64) {   // wave 0: greedy assignment on lanes 0..15
        const bool mine = (tid < 16);
        float total = 0.f;
        unsigned avail = mine ? 1u : 0u;
        for (int step = 0; step < 16; ++step) {
            float v = (mine && avail) ? L[step][tid] : 1e30f;
            int idx = tid;
            #pragma unroll
            for (int o = 8; o; o >>= 1) {
                const float ov = __shfl_xor(v, o, 64);
                const int   oi = __shfl_xor(idx, o, 64);
                if (ov < v || (ov == v && oi < idx)) { v = ov; idx = oi; }
            }
            if (tid == 0) total += v;
            if (tid == idx) avail = 0;
        }
        if (tid == 0) {
            const float cnt0 = Mf - s_fg;
            const float bce_c  = -acc[0] * LN2F / Mf;
            const float dice_c = 1.f - (2.f * acc[1] + EPSF) / (acc[2] + s_fg + EPSF);
            const float bce_0  = -acc[3] * LN2F / Mf;
            const float dice_0 = 1.f - (2.f * acc[4] + EPSF) / (acc[5] + cnt0 + EPSF);
            const float res = bce_c + dice_c + bce_0 + dice_0;
            out[0] = (res + total) / 16.f;
        }
    }
}

extern "C" void kernel_launch(void* const* d_in, const int* in_sizes, int n_in,
                              void* d_out, int out_size, void* d_ws, size_t ws_size,
                              hipStream_t stream)
{
    const float* pred = (const float*)d_in[0];
    const float* cls  = (const float*)d_in[1];
    const int*   tmi  = (const int*)d_in[2];
    float* acc = (float*)d_ws;

    hipMemsetAsync(d_ws, 0, 566 * sizeof(float), stream);

    loss_main<<<dim3(NBLK), 512, 0, stream>>>(pred, cls, tmi, acc);
    loss_final<<<1, 256, 0, stream>>>(acc, (float*)d_out);
}

// Round 11
// 66.319 us; speedup vs baseline: 1.2189x; 1.0466x over previous
//
#include <hip/hip_runtime.h>
#include <hip/hip_bf16.h>

#define HWPX 589824          // 768*768
#define MPIX 2359296         // 4*768*768
#define EPSF 1e-7f
#define LN2F 0.6931471805599453f
#define PXB  2304            // px per block; 256 blocks/image -> never straddles
#define NBLK 1024            // MPIX / PXB
#define MSTEPS 9             // 9 steps * (8 waves * 32 px) = 2304 px

// ws float layout:
// [0..2]   cls: bce_log2sum, inter, sum_p
// [3..5]   pred ch0 vs (1-tfg): bce_log2sum, inter, sum_p
// [6..21]  a_sum[k]  = sum log2(1-pc), channels k=0..15 (pred ch 1..16)
// [22..37] sum_p[k]
// [38..293]  segD[n*16+k]   (log2 units)
// [294..549] segP[n*16+k]
// [550..565] cntf[n]  float counts of ids 1..16

typedef __attribute__((ext_vector_type(8))) short bf16x8;
typedef __attribute__((ext_vector_type(4))) float f32x4;

__device__ __forceinline__ short bfc(float x) {   // compiler emits v_cvt_pk_bf16_f32
    union { __hip_bfloat16 h; short s; } u;
    u.h = __float2bfloat16(x);
    return u.s;
}

__device__ __forceinline__ float wave_sum64(float v) {
#pragma unroll
    for (int o = 32; o; o >>= 1) v += __shfl_xor(v, o, 64);
    return v;
}

// opaque loads: compiler cannot sink/merge these or free dst before use
#define ALOADF4(dst, addr) \
    asm volatile("global_load_dwordx4 %0, %1, off" : "=&v"(dst) : "v"(addr) : "memory")
#define ALOADI4(dst, addr) \
    asm volatile("global_load_dwordx4 %0, %1, off" : "=&v"(dst) : "v"(addr) : "memory")
// counted wait + scheduling fence (rule #18)
#define PIPE_WAIT(n) do { \
    asm volatile("s_waitcnt vmcnt(" #n ")" ::: "memory"); \
    __builtin_amdgcn_sched_barrier(0); } while (0)

struct Buf { float4 pa, pb; int4 ta, tb; };

__global__ __launch_bounds__(512, 4) void loss_main(
    const float* __restrict__ pred, const float* __restrict__ cls,
    const int* __restrict__ tm, float* __restrict__ acc)
{
    __shared__ float sD[8][256];     // per-wave segD C-frags
    __shared__ float sP[8][256];
    __shared__ float sCh[3][16][8];  // {sum_log2_1mp, sum_p, cnt}[ch/bin][wave]
    __shared__ float sC6[6][8];      // cls/ch0 partials

    const int tid  = threadIdx.x;
    const int w    = tid >> 6;       // wave 0..7
    const int lane = tid & 63;
    const int g    = lane >> 4;      // px subgroup 0..3
    const int q    = lane & 15;      // B: channel idx / A: bin idx

    const long base = (long)blockIdx.x * PXB;
    const int b   = (int)(base / HWPX);
    const int off = (int)(base % HWPX);

    const int*   trow = tm   + (long)b * HWPX + off;
    const float* prow = pred + ((long)b * 17 + 1 + q) * (long)HWPX + off;

    f32x4 aD = {0.f, 0.f, 0.f, 0.f};
    f32x4 aP = {0.f, 0.f, 0.f, 0.f};
    float sl2 = 0.f, sp = 0.f, cf = 0.f;
    const int tgt = q + 1;
    const int lbase = w * 32 + g * 8;

    Buf bf[3];   // all indices compile-time under full unroll
#define ISSUE(S, B) do { const int _px = lbase + (S) * 256;  \
        ALOADF4(bf[B].pa, prow + _px);                       \
        ALOADF4(bf[B].pb, prow + _px + 4);                   \
        ALOADI4(bf[B].ta, trow + _px);                       \
        ALOADI4(bf[B].tb, trow + _px + 4); } while (0)

    ISSUE(0, 0);
    ISSUE(1, 1);

#pragma unroll
    for (int s = 0; s < MSTEPS; ++s) {
        if (s + 2 < MSTEPS) {            // steady state: 12 outstanding, retire oldest 4
            ISSUE(s + 2, (s + 2) % 3);
            PIPE_WAIT(8);
        } else if (s + 1 < MSTEPS) {     // s = MSTEPS-2: groups s, s+1 outstanding
            PIPE_WAIT(4);
        } else {                         // s = MSTEPS-1: drain
            PIPE_WAIT(0);
        }
        const Buf& cb = bf[s % 3];
        const float pv[8] = {cb.pa.x,cb.pa.y,cb.pa.z,cb.pa.w,cb.pb.x,cb.pb.y,cb.pb.z,cb.pb.w};
        const int   tv[8] = {cb.ta.x,cb.ta.y,cb.ta.z,cb.ta.w,cb.tb.x,cb.tb.y,cb.tb.z,cb.tb.w};
        bf16x8 av, bD, bP;
#pragma unroll
        for (int j = 0; j < 8; ++j) {
            const float p  = pv[j];
            const float pc = fminf(fmaxf(p, EPSF), 1.0f - EPSF);
            const float l2p  = __log2f(pc);          // raw v_log_f32
            const float l21p = __log2f(1.0f - pc);
            sl2 += l21p;
            sp  += p;
            bD[j] = bfc(l21p - l2p);                 // log2-units; ln2 applied in finalize
            bP[j] = bfc(p);
            const bool m = (tv[j] == tgt);
            av[j] = m ? (short)0x3F80 : (short)0;
            cf += m ? 1.f : 0.f;
        }
        aD = __builtin_amdgcn_mfma_f32_16x16x32_bf16(av, bD, aD, 0, 0, 0);
        aP = __builtin_amdgcn_mfma_f32_16x16x32_bf16(av, bP, aP, 0, 0, 0);
    }
#undef ISSUE

    // reduce per-channel scalars across the 4 px-subgroups (lanes l, l^16, l^32, l^48)
    sl2 += __shfl_xor(sl2, 16, 64); sl2 += __shfl_xor(sl2, 32, 64);
    sp  += __shfl_xor(sp,  16, 64); sp  += __shfl_xor(sp,  32, 64);
    cf  += __shfl_xor(cf,  16, 64); cf  += __shfl_xor(cf,  32, 64);
    if (lane < 16) { sCh[0][q][w] = sl2; sCh[1][q][w] = sp; sCh[2][q][w] = cf; }

    *(f32x4*)&sD[w][lane * 4] = aD;   // element (n,k) at flat ((((n>>2)<<4)|k)<<2)|(n&3)
    *(f32x4*)&sP[w][lane * 4] = aP;

    // ---- cls (vs tfg) and pred ch0 (vs 1-tfg): 2304 px = 512*4 + 64*4 ----
    const float* crow = cls  + (long)b * HWPX + off;
    const float* zrow = pred + (long)b * 17 * (long)HWPX + off;   // channel 0
    float s0c=0.f,s1c=0.f,s2c=0.f, s00=0.f,s10=0.f,s20=0.f;
    const int nch = (tid < 64) ? 2 : 1;
    for (int chunk = 0; chunk < nch; ++chunk) {
        const int pbase = (chunk == 0) ? tid * 4 : 2048 + tid * 4;
        const float4 ca = *(const float4*)(crow + pbase);
        const float4 za = *(const float4*)(zrow + pbase);
        const int4   ua = *(const int4*)(trow + pbase);
        const float cv[4] = {ca.x,ca.y,ca.z,ca.w};
        const float zv[4] = {za.x,za.y,za.z,za.w};
        const int   uv[4] = {ua.x,ua.y,ua.z,ua.w};
#pragma unroll
        for (int j = 0; j < 4; ++j) {
            const int t = uv[j];
            { const float p = cv[j];
              const float pc = fminf(fmaxf(p, EPSF), 1.0f - EPSF);
              const float lp = __log2f(pc), l1p = __log2f(1.0f - pc);
              const bool fg = (t > 0);
              s0c += fg ? lp : l1p; s1c += fg ? p : 0.f; s2c += p; }
            { const float p = zv[j];
              const float pc = fminf(fmaxf(p, EPSF), 1.0f - EPSF);
              const float lp = __log2f(pc), l1p = __log2f(1.0f - pc);
              const bool bg = (t == 0);
              s00 += bg ? lp : l1p; s10 += bg ? p : 0.f; s20 += p; }
        }
    }
    s0c = wave_sum64(s0c); s1c = wave_sum64(s1c); s2c = wave_sum64(s2c);
    s00 = wave_sum64(s00); s10 = wave_sum64(s10); s20 = wave_sum64(s20);
    if (lane == 0) {
        sC6[0][w]=s0c; sC6[1][w]=s1c; sC6[2][w]=s2c;
        sC6[3][w]=s00; sC6[4][w]=s10; sC6[5][w]=s20;
    }
    __syncthreads();

    if (tid < 256) {
        const int n = tid >> 4, k = tid & 15;
        const int idx = ((((n >> 2) << 4) | k) << 2) | (n & 3);
        float dsum = 0.f, psum = 0.f;
#pragma unroll
        for (int ww = 0; ww < 8; ++ww) { dsum += sD[ww][idx]; psum += sP[ww][idx]; }
        atomicAdd(&acc[38 + n * 16 + k], dsum);
        atomicAdd(&acc[294 + n * 16 + k], psum);
    } else if (tid < 304) {
        const int i = tid - 256, qq = i >> 4, ii = i & 15;
        float t = 0.f;
#pragma unroll
        for (int ww = 0; ww < 8; ++ww) t += sCh[qq][ii][ww];
        atomicAdd(&acc[(qq == 0) ? (6 + ii) : (qq == 1) ? (22 + ii) : (550 + ii)], t);
    } else if (tid < 310) {
        const int i = tid - 304;
        float t = 0.f;
#pragma unroll
        for (int ww = 0; ww < 8; ++ww) t += sC6[i][ww];
        atomicAdd(&acc[i], t);
    }
}

__global__ void loss_final(const float* __restrict__ acc, float* __restrict__ out)
{
    __shared__ float L[16][16];
    __shared__ float s_fg;
    const int tid = threadIdx.x;
    const float Mf = (float)MPIX;

    if (tid == 0) {
        float s = 0.f;
        for (int n = 0; n < 16; ++n) s += acc[550 + n];
        s_fg = s;                      // # pixels with id>0 == sum(tfg)
    }
    __syncthreads();

    if (tid < 256) {
        const int n = tid >> 4, k = tid & 15;
        const float segD = acc[38 + n * 16 + k];    // log2 units
        const float segP = acc[294 + n * 16 + k];
        const float sump = acc[22 + k];
        const float cn   = acc[550 + n];
        const float bce  = (segD - acc[6 + k]) * LN2F / Mf;
        const float dice = 1.f - (2.f * segP + EPSF) / (sump + cn + EPSF);
        L[n][k] = bce + dice;
    }
    __syncthreads();

    if (tid < 64) {   // wave 0: greedy assignment on lanes 0..15
        const bool mine = (tid < 16);
        float total = 0.f;
        unsigned avail = mine ? 1u : 0u;
        for (int step = 0; step < 16; ++step) {
            float v = (mine && avail) ? L[step][tid] : 1e30f;
            int idx = tid;
            #pragma unroll
            for (int o = 8; o; o >>= 1) {
                const float ov = __shfl_xor(v, o, 64);
                const int   oi = __shfl_xor(idx, o, 64);
                if (ov < v || (ov == v && oi < idx)) { v = ov; idx = oi; }
            }
            if (tid == 0) total += v;
            if (tid == idx) avail = 0;
        }
        if (tid == 0) {
            const float cnt0 = Mf - s_fg;
            const float bce_c  = -acc[0] * LN2F / Mf;
            const float dice_c = 1.f - (2.f * acc[1] + EPSF) / (acc[2] + s_fg + EPSF);
            const float bce_0  = -acc[3] * LN2F / Mf;
            const float dice_0 = 1.f - (2.f * acc[4] + EPSF) / (acc[5] + cnt0 + EPSF);
            const float res = bce_c + dice_c + bce_0 + dice_0;
            out[0] = (res + total) / 16.f;
        }
    }
}

extern "C" void kernel_launch(void* const* d_in, const int* in_sizes, int n_in,
                              void* d_out, int out_size, void* d_ws, size_t ws_size,
                              hipStream_t stream)
{
    const float* pred = (const float*)d_in[0];
    const float* cls  = (const float*)d_in[1];
    const int*   tmi  = (const int*)d_in[2];
    float* acc = (float*)d_ws;

    hipMemsetAsync(d_ws, 0, 566 * sizeof(float), stream);

    loss_main<<<dim3(NBLK), 512, 0, stream>>>(pred, cls, tmi, acc);
    loss_final<<<1, 256, 0, stream>>>(acc, (float*)d_out);
}